// Round 10
// baseline (257.905 us; speedup 1.0000x reference)
//
#include <hip/hip_runtime.h>
#include <hip/hip_bf16.h>

// MultiHeadedAttention: B=4, T=2048, F=1024, h=16, dk=64.
// weights cvt -> merged QKV GEMM (dbuf pipeline, fused f32->bf16 A-staging,
// LDS-bounce epilogues; Q pre-scaled, V transposed) -> attn v5 -> out GEMM (dbuf).

typedef unsigned short u16;
typedef unsigned long long u64;
typedef __attribute__((ext_vector_type(8))) short short8;
typedef __attribute__((ext_vector_type(4))) float f32x4;
typedef __attribute__((ext_vector_type(16))) float f32x16;
typedef __attribute__((ext_vector_type(4))) unsigned int u32x4;

#define GLOAD16(g, l) __builtin_amdgcn_global_load_lds( \
    (const __attribute__((address_space(1))) unsigned int*)(g), \
    (__attribute__((address_space(3))) unsigned int*)(l), 16, 0, 0)

__device__ __forceinline__ u16 f2bf(float x) {
  unsigned int u = __float_as_uint(x);
  return (u16)((u + 0x7fffu + ((u >> 16) & 1u)) >> 16);  // RNE, finite inputs
}

__device__ __forceinline__ float fexp2(float x) {
#if __has_builtin(__builtin_amdgcn_exp2f)
  return __builtin_amdgcn_exp2f(x);
#else
  return exp2f(x);
#endif
}

__device__ __forceinline__ unsigned cvtpk(float lo, float hi) {
  unsigned r;
  asm("v_cvt_pk_bf16_f32 %0, %1, %2" : "=v"(r) : "v"(lo), "v"(hi));
  return r;
}

// ---------------- f32 -> bf16 multi-tensor convert (weights) ----------------
struct CvtArgs {
  const float* src[4];
  u16* dst[4];
};

__global__ __launch_bounds__(256) void cvt_multi(CvtArgs a, int shift) {
  const int id = blockIdx.x * 256 + threadIdx.x;
  const int seg = id >> shift;
  const int off = id & ((1 << shift) - 1);
  float4 v = ((const float4*)a.src[seg])[off];
  ushort4 o;
  o.x = f2bf(v.x); o.y = f2bf(v.y); o.z = f2bf(v.z); o.w = f2bf(v.w);
  ((ushort4*)a.dst[seg])[off] = o;
}

// ---------------- merged QKV projection GEMM ----------------
// Grid 1536 = 3 segs x 512 blocks; 128x128 tile, BK=64, 4 waves, dbuf LDS 64KB.
// A f32 staged via regs (load->cvtpk->ds_write bf16). One __syncthreads per K-iter.
// Epilogue via LDS bounce: seg 0/1 -> [B,h,T,dk] bf16 (seg0 scaled); seg 2 -> [B,h,dk,T].
struct QKVArgs {
  const float* A[3];
  const u16* W[3];
  const float* bias[3];
  u16* out[3];
};

__global__ __launch_bounds__(256, 2) void qkv_gemm(QKVArgs args) {
  __shared__ __align__(16) char smem[65536];  // As[2]@0,16K; Bs[2]@32K,48K; bounce overlay

  const int t = threadIdx.x, lane = t & 63, w = t >> 6;
  const int wm = w >> 1, wn = w & 1;
  const int l15 = lane & 15, l4 = lane >> 4;

  const int bid = blockIdx.x;
  const int seg = bid >> 9;
  const int inner = bid & 511;
  const int swz = (inner & 7) * 64 + (inner >> 3);
  const int brow = swz >> 3;  // 64 M-tiles
  const int bcol = swz & 7;   // 8 N-tiles

  const float* Ag = args.A[seg];
  const u16* Wg = args.W[seg];
  const float* bias = args.bias[seg];
  u16* outp = args.out[seg];
  const float scale = (seg == 0) ? 0.18033688011112042f : 1.0f;  // (1/8)*log2e for Q

  const int arow = t >> 1;           // 0..127 (A reg-staging row)
  const int as0 = (t & 1) * 4;       // chunk base 0/4
  const int srow = t >> 3;           // B staging
  const int sbyte = (t & 7) * 16;

  f32x4 acc[4][4] = {};
  float4 areg[8];

#define ALOAD(k0)                                                                \
  {                                                                              \
    const float4* p = (const float4*)(Ag + (size_t)(brow * 128 + arow) * 1024 +  \
                                      (k0) + as0 * 8);                           \
    _Pragma("unroll") for (int j = 0; j < 8; ++j) areg[j] = p[j];                \
  }
#define AWRITE(bufptr)                                                           \
  {                                                                              \
    _Pragma("unroll") for (int i = 0; i < 4; ++i) {                              \
      u32x4 pk = {cvtpk(areg[2 * i].x, areg[2 * i].y),                           \
                  cvtpk(areg[2 * i].z, areg[2 * i].w),                           \
                  cvtpk(areg[2 * i + 1].x, areg[2 * i + 1].y),                   \
                  cvtpk(areg[2 * i + 1].z, areg[2 * i + 1].w)};                  \
      *(u32x4*)((char*)(bufptr) + arow * 128 +                                   \
                (((as0 + i) * 16) ^ ((arow & 7) << 4))) = pk;                    \
    }                                                                            \
  }
#define STAGEB(bufptr, Bsrc, colbase, k0)                                        \
  {                                                                              \
    _Pragma("unroll") for (int i = 0; i < 4; ++i) {                              \
      const int r = i * 32 + srow;                                               \
      const int sb = sbyte ^ ((r & 7) << 4);                                     \
      GLOAD16((const char*)(Bsrc + (size_t)((colbase) + r) * 1024 + (k0)) + sb,  \
              (char*)(bufptr) + i * 4096 + t * 16);                              \
    }                                                                            \
  }

  // prologue: tile 0
  ALOAD(0);
  STAGEB(smem + 32768, Wg, bcol * 128, 0);
  AWRITE(smem);
  __syncthreads();

  int buf = 0;
  for (int kt = 0; kt < 16; ++kt) {
    if (kt < 15) {
      ALOAD(kt * 64 + 64);
      STAGEB(smem + 32768 + ((buf ^ 1) << 14), Wg, bcol * 128, kt * 64 + 64);
    }
    const char* Ab = smem + (buf << 14);
    const char* Bb = smem + 32768 + (buf << 14);
#pragma unroll
    for (int kf = 0; kf < 2; ++kf) {
      short8 af[4], bfv[4];
#pragma unroll
      for (int mi = 0; mi < 4; ++mi) {
        const int r = wm * 64 + mi * 16 + l15;
        af[mi] = *(const short8*)(Ab + r * 128 + ((kf * 64 + l4 * 16) ^ ((r & 7) << 4)));
      }
#pragma unroll
      for (int ni = 0; ni < 4; ++ni) {
        const int r = wn * 64 + ni * 16 + l15;
        bfv[ni] = *(const short8*)(Bb + r * 128 + ((kf * 64 + l4 * 16) ^ ((r & 7) << 4)));
      }
      __builtin_amdgcn_s_setprio(1);
#pragma unroll
      for (int mi = 0; mi < 4; ++mi)
#pragma unroll
        for (int ni = 0; ni < 4; ++ni)
          acc[mi][ni] = __builtin_amdgcn_mfma_f32_16x16x32_bf16(
              af[mi], bfv[ni], acc[mi][ni], 0, 0, 0);
      __builtin_amdgcn_s_setprio(0);
    }
    if (kt < 15) AWRITE(smem + ((buf ^ 1) << 14));
    __syncthreads();  // buf^1 staging (B gloads + A ds_writes) complete; reads done
    buf ^= 1;
  }
#undef ALOAD
#undef AWRITE

  // ---- epilogue via LDS bounce (overlay smem; loop's final barrier freed it) ----
  u16* cb = (u16*)smem;  // padded tile [128][136] u16 = 34816 B
  const int bglob = brow >> 4;
  const int tokbase = (brow & 15) * 128;

  if (seg < 2) {
    // layout [m][n]; store rows of [B,h,T,dk] (d contiguous)
#pragma unroll
    for (int ni = 0; ni < 4; ++ni) {
      const int n = wn * 64 + ni * 16 + l15;
      const float b = bias[bcol * 128 + n];
#pragma unroll
      for (int mi = 0; mi < 4; ++mi) {
        const int m0 = wm * 64 + mi * 16 + l4 * 4;
#pragma unroll
        for (int r = 0; r < 4; ++r)
          cb[(m0 + r) * 136 + n] = f2bf((acc[mi][ni][r] + b) * scale);
      }
    }
    __syncthreads();
#pragma unroll
    for (int j = 0; j < 8; ++j) {
      const int c = t + 256 * j;
      const int m = c >> 4, nc = c & 15;
      u32x4 v = *(const u32x4*)(cb + m * 136 + nc * 8);
      const int ng = bcol * 128 + nc * 8;
      const int h = ng >> 6, d0 = ng & 63;
      *(u32x4*)(outp + (((size_t)(bglob * 16 + h) * 2048 + tokbase + m) << 6) + d0) = v;
    }
  } else {
    // layout [n][m]; store rows of [B,h,dk,T] (tok contiguous)
#pragma unroll
    for (int ni = 0; ni < 4; ++ni) {
      const int n = wn * 64 + ni * 16 + l15;
      const float b = bias[bcol * 128 + n];
#pragma unroll
      for (int mi = 0; mi < 4; ++mi) {
        const int m0 = wm * 64 + mi * 16 + l4 * 4;
        ushort4 pk4;
        pk4.x = f2bf(acc[mi][ni][0] + b);
        pk4.y = f2bf(acc[mi][ni][1] + b);
        pk4.z = f2bf(acc[mi][ni][2] + b);
        pk4.w = f2bf(acc[mi][ni][3] + b);
        *(ushort4*)(cb + n * 136 + m0) = pk4;
      }
    }
    __syncthreads();
#pragma unroll
    for (int j = 0; j < 8; ++j) {
      const int c = t + 256 * j;
      const int n = c >> 4, mc = c & 15;
      u32x4 v = *(const u32x4*)(cb + n * 136 + mc * 8);
      const int ng = bcol * 128 + n;
      const int h = ng >> 6, d = ng & 63;
      *(u32x4*)(outp + (((size_t)(bglob * 16 + h) * 64 + d) << 11) + tokbase + mc * 8) = v;
    }
  }
}

// ---------------- output projection GEMM (bf16 A, f32 out, dbuf pipeline) ----------------
__global__ __launch_bounds__(256, 2) void out_gemm(const u16* __restrict__ A,
                                                   const u16* __restrict__ Wg,
                                                   const float* __restrict__ bias,
                                                   float* __restrict__ outp) {
  __shared__ __align__(16) char smem[65536];

  const int t = threadIdx.x, lane = t & 63, w = t >> 6;
  const int wm = w >> 1, wn = w & 1;
  const int l15 = lane & 15, l4 = lane >> 4;

  const int bid = blockIdx.x;
  const int swz = (bid & 7) * 64 + (bid >> 3);
  const int brow = swz >> 3;
  const int bcol = swz & 7;

  const int srow = t >> 3;
  const int sbyte = (t & 7) * 16;

  f32x4 acc[4][4] = {};

  STAGEB(smem, A, brow * 128, 0);
  STAGEB(smem + 32768, Wg, bcol * 128, 0);
  __syncthreads();

  int buf = 0;
  for (int kt = 0; kt < 16; ++kt) {
    if (kt < 15) {
      STAGEB(smem + ((buf ^ 1) << 14), A, brow * 128, kt * 64 + 64);
      STAGEB(smem + 32768 + ((buf ^ 1) << 14), Wg, bcol * 128, kt * 64 + 64);
    }
    const char* Ab = smem + (buf << 14);
    const char* Bb = smem + 32768 + (buf << 14);
#pragma unroll
    for (int kf = 0; kf < 2; ++kf) {
      short8 af[4], bfv[4];
#pragma unroll
      for (int mi = 0; mi < 4; ++mi) {
        const int r = wm * 64 + mi * 16 + l15;
        af[mi] = *(const short8*)(Ab + r * 128 + ((kf * 64 + l4 * 16) ^ ((r & 7) << 4)));
      }
#pragma unroll
      for (int ni = 0; ni < 4; ++ni) {
        const int r = wn * 64 + ni * 16 + l15;
        bfv[ni] = *(const short8*)(Bb + r * 128 + ((kf * 64 + l4 * 16) ^ ((r & 7) << 4)));
      }
      __builtin_amdgcn_s_setprio(1);
#pragma unroll
      for (int mi = 0; mi < 4; ++mi)
#pragma unroll
        for (int ni = 0; ni < 4; ++ni)
          acc[mi][ni] = __builtin_amdgcn_mfma_f32_16x16x32_bf16(
              af[mi], bfv[ni], acc[mi][ni], 0, 0, 0);
      __builtin_amdgcn_s_setprio(0);
    }
    __syncthreads();
    buf ^= 1;
  }
#undef STAGEB

  // direct f32 store (4B elements: 64B/16-lane segments, acceptable)
#pragma unroll
  for (int ni = 0; ni < 4; ++ni) {
    const int n = bcol * 128 + wn * 64 + ni * 16 + l15;
    const float bn = bias[n];
#pragma unroll
    for (int mi = 0; mi < 4; ++mi) {
      const int mb = brow * 128 + wm * 64 + mi * 16 + l4 * 4;
#pragma unroll
      for (int r = 0; r < 4; ++r)
        outp[(size_t)(mb + r) * 1024 + n] = acc[mi][ni][r] + bn;
    }
  }
}

// ---------------- Flash attention v5 (R6/R9, 111.9 us) ----------------
__global__ __launch_bounds__(256, 2) void attn_fwd5(const u16* __restrict__ Q,
                                                    const u16* __restrict__ Kp,
                                                    const u16* __restrict__ Vt,
                                                    const int* __restrict__ mask,
                                                    u16* __restrict__ ctx) {
  __shared__ u16 Ks[2][64 * 64];
  __shared__ u16 Vs[2][64 * 64];

  const int t = threadIdx.x, lane = t & 63, w = t >> 6;
  const int q31 = lane & 31, hi = lane >> 5;

  const int bid = blockIdx.x;
  const int swz = (bid & 7) * 64 + (bid >> 3);
  const int bh = swz >> 3;
  const int b_ = bh >> 4, h_ = bh & 15;
  const int q0 = (swz & 7) * 256 + w * 64;
  const size_t headO = (size_t)bh * 131072;

  short8 qfA[4], qfB[4];
  {
    const u16* qrowA = Q + headO + (size_t)(q0 + q31) * 64 + hi * 8;
    const u16* qrowB = qrowA + 32 * 64;
#pragma unroll
    for (int ds = 0; ds < 4; ++ds) {
      qfA[ds] = *(const short8*)(qrowA + ds * 16);
      qfB[ds] = *(const short8*)(qrowB + ds * 16);
    }
  }

  const int srow = t >> 3;
  const int sbyte = (t & 7) * 16;

#define STAGE_KV(bufi, kb)                                                      \
  {                                                                             \
    _Pragma("unroll") for (int i = 0; i < 2; ++i) {                             \
      const int r = i * 32 + srow;                                              \
      const int sb = sbyte ^ ((r & 7) << 4);                                    \
      GLOAD16((const char*)(Kp + headO + (size_t)((kb) + r) * 64) + sb,         \
              &Ks[bufi][(i * 4096 + t * 16) >> 1]);                             \
      GLOAD16((const char*)(Vt + headO + (size_t)r * 2048 + (kb)) + sb,         \
              &Vs[bufi][(i * 4096 + t * 16) >> 1]);                             \
    }                                                                           \
  }

#define PACK(sv, pfa, pfb)                                                      \
  {                                                                             \
    const unsigned w0 = cvtpk(sv[0], sv[1]),   w1 = cvtpk(sv[2], sv[3]);        \
    const unsigned w2 = cvtpk(sv[4], sv[5]),   w3 = cvtpk(sv[6], sv[7]);        \
    const unsigned w4 = cvtpk(sv[8], sv[9]),   w5 = cvtpk(sv[10], sv[11]);      \
    const unsigned w6 = cvtpk(sv[12], sv[13]), w7 = cvtpk(sv[14], sv[15]);      \
    const unsigned x0 = (unsigned)__shfl_xor((int)(hi ? w0 : w2), 32);          \
    const unsigned x1 = (unsigned)__shfl_xor((int)(hi ? w1 : w3), 32);          \
    const unsigned y0 = (unsigned)__shfl_xor((int)(hi ? w4 : w6), 32);          \
    const unsigned y1 = (unsigned)__shfl_xor((int)(hi ? w5 : w7), 32);          \
    u32x4 fa = hi ? (u32x4){x0, x1, w2, w3} : (u32x4){w0, w1, x0, x1};          \
    u32x4 fb = hi ? (u32x4){y0, y1, w6, w7} : (u32x4){w4, w5, y0, y1};          \
    pfa = __builtin_bit_cast(short8, fa);                                       \
    pfb = __builtin_bit_cast(short8, fb);                                       \
  }

  f32x16 oA0 = {}, oA1 = {}, oB0 = {}, oB1 = {};
  float lA = 0.f, lB = 0.f;
  const int kcol = hi * 16;
  const int rswz = (q31 & 7) << 4;

  STAGE_KV(0, 0);
  int mk = mask[b_ * 2048 + lane];
  __syncthreads();

  int buf = 0;
  for (int kt = 0; kt < 32; ++kt) {
    const int kb = kt * 64;
    if (kt + 1 < 32) STAGE_KV(buf ^ 1, kb + 64);
    const int mk_next = (kt + 1 < 32) ? mask[b_ * 2048 + kb + 64 + lane] : 0;
    const u64 bits = __ballot(mk != 0);

#pragma unroll
    for (int half = 0; half < 2; ++half) {
      f32x16 sA = {}, sB = {};
      __builtin_amdgcn_s_setprio(1);
#pragma unroll
      for (int ds = 0; ds < 4; ++ds) {
        const int byt = (half * 32 + q31) * 128 + ((ds * 32 + kcol) ^ rswz);
        short8 ka = *(const short8*)&Ks[buf][byt >> 1];
        sA = __builtin_amdgcn_mfma_f32_32x32x16_bf16(ka, qfA[ds], sA, 0, 0, 0);
        sB = __builtin_amdgcn_mfma_f32_32x32x16_bf16(ka, qfB[ds], sB, 0, 0, 0);
      }
      __builtin_amdgcn_s_setprio(0);

      if (bits == ~0ull) {
#pragma unroll
        for (int r = 0; r < 16; ++r) { sA[r] = fexp2(sA[r]); sB[r] = fexp2(sB[r]); }
      } else {
#pragma unroll
        for (int r = 0; r < 16; ++r) {
          const int k0 = half * 32 + (r & 3) + 8 * (r >> 2) + 4 * hi;
          const bool on = (bits >> k0) & 1;
          sA[r] = on ? fexp2(sA[r]) : 0.f;
          sB[r] = on ? fexp2(sB[r]) : 0.f;
        }
      }

      {
        float a0 = 0.f, a1 = 0.f, b0 = 0.f, b1 = 0.f;
#pragma unroll
        for (int r = 0; r < 16; r += 2) {
          a0 += sA[r]; a1 += sA[r + 1];
          b0 += sB[r]; b1 += sB[r + 1];
        }
        lA += a0 + a1;
        lB += b0 + b1;
      }

      short8 pA0, pA1, pB0, pB1;
      PACK(sA, pA0, pA1);
      PACK(sB, pB0, pB1);

      __builtin_amdgcn_s_setprio(1);
      {
        const int rb0 = q31 * 128, rb1 = (32 + q31) * 128;
        const int c0 = (half * 64 + kcol) ^ rswz;
        const int c1 = (half * 64 + 32 + kcol) ^ rswz;
        short8 va;
        va = *(const short8*)&Vs[buf][(rb0 + c0) >> 1];
        oA0 = __builtin_amdgcn_mfma_f32_32x32x16_bf16(va, pA0, oA0, 0, 0, 0);
        oB0 = __builtin_amdgcn_mfma_f32_32x32x16_bf16(va, pB0, oB0, 0, 0, 0);
        va = *(const short8*)&Vs[buf][(rb0 + c1) >> 1];
        oA0 = __builtin_amdgcn_mfma_f32_32x32x16_bf16(va, pA1, oA0, 0, 0, 0);
        oB0 = __builtin_amdgcn_mfma_f32_32x32x16_bf16(va, pB1, oB0, 0, 0, 0);
        va = *(const short8*)&Vs[buf][(rb1 + c0) >> 1];
        oA1 = __builtin_amdgcn_mfma_f32_32x32x16_bf16(va, pA0, oA1, 0, 0, 0);
        oB1 = __builtin_amdgcn_mfma_f32_32x32x16_bf16(va, pB0, oB1, 0, 0, 0);
        va = *(const short8*)&Vs[buf][(rb1 + c1) >> 1];
        oA1 = __builtin_amdgcn_mfma_f32_32x32x16_bf16(va, pA1, oA1, 0, 0, 0);
        oB1 = __builtin_amdgcn_mfma_f32_32x32x16_bf16(va, pB1, oB1, 0, 0, 0);
      }
      __builtin_amdgcn_s_setprio(0);
    }

    mk = mk_next;
    __syncthreads();
    buf ^= 1;
  }
#undef STAGE_KV

  lA += __shfl_xor(lA, 32);
  lB += __shfl_xor(lB, 32);
  const float invA = lA > 0.f ? 1.f / lA : 0.f;
  const float invB = lB > 0.f ? 1.f / lB : 0.f;
  const int tokA = q0 + q31;
  u16* crowA = ctx + ((size_t)b_ * 2048 + tokA) * 1024 + h_ * 64 + 4 * hi;
  u16* crowB = crowA + 32 * 1024;
#pragma unroll
  for (int g = 0; g < 4; ++g) {
    unsigned u0, u1;
    u0 = cvtpk(oA0[4 * g + 0] * invA, oA0[4 * g + 1] * invA);
    u1 = cvtpk(oA0[4 * g + 2] * invA, oA0[4 * g + 3] * invA);
    *(uint2*)(crowA + 8 * g) = make_uint2(u0, u1);
    u0 = cvtpk(oA1[4 * g + 0] * invA, oA1[4 * g + 1] * invA);
    u1 = cvtpk(oA1[4 * g + 2] * invA, oA1[4 * g + 3] * invA);
    *(uint2*)(crowA + 32 + 8 * g) = make_uint2(u0, u1);
    u0 = cvtpk(oB0[4 * g + 0] * invB, oB0[4 * g + 1] * invB);
    u1 = cvtpk(oB0[4 * g + 2] * invB, oB0[4 * g + 3] * invB);
    *(uint2*)(crowB + 8 * g) = make_uint2(u0, u1);
    u0 = cvtpk(oB1[4 * g + 0] * invB, oB1[4 * g + 1] * invB);
    u1 = cvtpk(oB1[4 * g + 2] * invB, oB1[4 * g + 3] * invB);
    *(uint2*)(crowB + 32 + 8 * g) = make_uint2(u0, u1);
  }
}

// ---------------- host launcher ----------------
extern "C" void kernel_launch(void* const* d_in, const int* in_sizes, int n_in,
                              void* d_out, int out_size, void* d_ws, size_t ws_size,
                              hipStream_t stream) {
  const float* q_in = (const float*)d_in[0];
  const float* k_in = (const float*)d_in[1];
  const float* v_in = (const float*)d_in[2];
  const int*   mask = (const int*)d_in[3];
  const float* Wq = (const float*)d_in[4];
  const float* bq = (const float*)d_in[5];
  const float* Wk = (const float*)d_in[6];
  const float* bk = (const float*)d_in[7];
  const float* Wv = (const float*)d_in[8];
  const float* bv = (const float*)d_in[9];
  const float* Wo = (const float*)d_in[10];
  const float* bo = (const float*)d_in[11];
  float* out = (float*)d_out;

  char* ws = (char*)d_ws;
  u16* ctx = (u16*)(ws);                       // [B,T,F] bf16 attn output
  u16* Qp = (u16*)(ws + 50331648);             // [B,h,T,dk], pre-scaled
  u16* Kp = (u16*)(ws + 67108864);             // [B,h,T,dk]
  u16* Vtb = (u16*)(ws + 83886080);            // [B,h,dk,T]
  u16* wqb = (u16*)(ws + 100663296);           // bf16 weights, 2 MiB each
  u16* wkb = (u16*)(ws + 102760448);
  u16* wvb = (u16*)(ws + 104857600);
  u16* wob = (u16*)(ws + 106954752);

  // weights f32 -> bf16 (4 x 2^18 float4)
  CvtArgs wts;
  wts.src[0] = Wq;  wts.src[1] = Wk;  wts.src[2] = Wv;  wts.src[3] = Wo;
  wts.dst[0] = wqb; wts.dst[1] = wkb; wts.dst[2] = wvb; wts.dst[3] = wob;
  cvt_multi<<<4 * 1024, 256, 0, stream>>>(wts, 18);

  // merged Q/K/V projections (f32 A fused-convert; Q pre-scaled; V transposed)
  QKVArgs qa;
  qa.A[0] = q_in; qa.A[1] = k_in; qa.A[2] = v_in;
  qa.W[0] = wqb;  qa.W[1] = wkb;  qa.W[2] = wvb;
  qa.bias[0] = bq; qa.bias[1] = bk; qa.bias[2] = bv;
  qa.out[0] = Qp;  qa.out[1] = Kp;  qa.out[2] = Vtb;
  qkv_gemm<<<1536, 256, 0, stream>>>(qa);

  attn_fwd5<<<512, 256, 0, stream>>>(Qp, Kp, Vtb, mask, ctx);

  out_gemm<<<512, 256, 0, stream>>>(ctx, wob, bo, out);
}

// Round 11
// 225.514 us; speedup vs baseline: 1.1436x; 1.1436x over previous
//
#include <hip/hip_runtime.h>
#include <hip/hip_bf16.h>

// MultiHeadedAttention: B=4, T=2048, F=1024, h=16, dk=64.
// weights cvt -> merged QKV GEMM (R9 structure: f32 A staged via global_load_lds,
// per-fragment cvt; Q pre-scaled, V transposed) -> attn v5 -> out GEMM (R9).

typedef unsigned short u16;
typedef unsigned long long u64;
typedef __attribute__((ext_vector_type(8))) short short8;
typedef __attribute__((ext_vector_type(4))) float f32x4;
typedef __attribute__((ext_vector_type(16))) float f32x16;
typedef __attribute__((ext_vector_type(4))) unsigned int u32x4;

#define GLOAD16(g, l) __builtin_amdgcn_global_load_lds( \
    (const __attribute__((address_space(1))) unsigned int*)(g), \
    (__attribute__((address_space(3))) unsigned int*)(l), 16, 0, 0)

__device__ __forceinline__ u16 f2bf(float x) {
  unsigned int u = __float_as_uint(x);
  return (u16)((u + 0x7fffu + ((u >> 16) & 1u)) >> 16);  // RNE, finite inputs
}

__device__ __forceinline__ float fexp2(float x) {
#if __has_builtin(__builtin_amdgcn_exp2f)
  return __builtin_amdgcn_exp2f(x);
#else
  return exp2f(x);
#endif
}

__device__ __forceinline__ unsigned cvtpk(float lo, float hi) {
  unsigned r;
  asm("v_cvt_pk_bf16_f32 %0, %1, %2" : "=v"(r) : "v"(lo), "v"(hi));
  return r;
}

// ---------------- f32 -> bf16 multi-tensor convert (weights) ----------------
struct CvtArgs {
  const float* src[4];
  u16* dst[4];
};

__global__ __launch_bounds__(256) void cvt_multi(CvtArgs a, int shift) {
  const int id = blockIdx.x * 256 + threadIdx.x;
  const int seg = id >> shift;
  const int off = id & ((1 << shift) - 1);
  float4 v = ((const float4*)a.src[seg])[off];
  ushort4 o;
  o.x = f2bf(v.x); o.y = f2bf(v.y); o.z = f2bf(v.z); o.w = f2bf(v.w);
  ((ushort4*)a.dst[seg])[off] = o;
}

// ---------------- merged QKV projection GEMM (R9 structure, seg-indexed) ----------------
// Grid 1536 = 3 segs x 512 blocks. 128x128 tile, BK=64, 4 waves (2x2), 2-barrier loop.
// A f32 staged raw via global_load_lds (granule-XOR swizzle r&15), cvt at fragment read.
// seg 0: out [B,h,T,dk] scaled by (1/8)*log2e.  seg 1: out [B,h,T,dk].
// seg 2: out [B,h,dk,T] (transposed V).
struct QKVArgs {
  const float* A[3];
  const u16* W[3];
  const float* bias[3];
  u16* out[3];
};

__global__ __launch_bounds__(256) void qkv3_gemm(QKVArgs args) {
  __shared__ __align__(16) char As[32768];  // f32 128x64
  __shared__ __align__(16) char Bs[16384];  // bf16 128x64

  const int t = threadIdx.x;
  const int lane = t & 63;
  const int w = t >> 6;
  const int wm = w >> 1, wn = w & 1;
  const int l15 = lane & 15, l4 = lane >> 4;

  const int bid = blockIdx.x;
  const int seg = bid >> 9;
  const int inner = bid & 511;
  const int swz = (inner & 7) * 64 + (inner >> 3);
  const int brow = swz >> 3;  // 64 M-tiles
  const int bcol = swz & 7;   // 8 N-tiles

  const float* Ag = args.A[seg];
  const u16* Wg = args.W[seg];
  const float* bias = args.bias[seg];
  u16* outp = args.out[seg];
  const float scale = (seg == 0) ? 0.18033688011112042f : 1.0f;

  f32x4 acc[4][4] = {};

  const int srow = t >> 3;          // 0..31   (bf16 B staging)
  const int sbyte = (t & 7) * 16;   // 0..112
  const int srowA = t >> 4;         // 0..15   (f32 A staging)
  const int sbyteA = (t & 15) * 16; // 0..240

  for (int kt = 0; kt < 16; ++kt) {
    const int k0 = kt * 64;
    __syncthreads();
#pragma unroll
    for (int i = 0; i < 8; ++i) {
      const int r = i * 16 + srowA;
      const int sb = sbyteA ^ ((r & 15) << 4);
      GLOAD16((const char*)(Ag + (size_t)(brow * 128 + r) * 1024 + k0) + sb,
              As + i * 4096 + t * 16);
    }
#pragma unroll
    for (int i = 0; i < 4; ++i) {
      const int r = i * 32 + srow;
      const int sb = sbyte ^ ((r & 7) << 4);
      GLOAD16((const char*)(Wg + (size_t)(bcol * 128 + r) * 1024 + k0) + sb,
              Bs + i * 4096 + t * 16);
    }
    __syncthreads();
#pragma unroll
    for (int kf = 0; kf < 2; ++kf) {
      short8 af[4], bfv[4];
#pragma unroll
      for (int mi = 0; mi < 4; ++mi) {
        const int r = wm * 64 + mi * 16 + l15;
        const int base = r * 256;
        const int cb = kf * 128 + l4 * 32;
        const int m0 = (r & 15) << 4;
        float4 x = *(const float4*)(As + base + ((cb) ^ m0));
        float4 y = *(const float4*)(As + base + ((cb + 16) ^ m0));
        u32x4 p = {cvtpk(x.x, x.y), cvtpk(x.z, x.w),
                   cvtpk(y.x, y.y), cvtpk(y.z, y.w)};
        af[mi] = __builtin_bit_cast(short8, p);
      }
#pragma unroll
      for (int ni = 0; ni < 4; ++ni) {
        const int r = wn * 64 + ni * 16 + l15;
        const int byt = r * 128 + ((kf * 64 + l4 * 16) ^ ((r & 7) << 4));
        bfv[ni] = *(const short8*)(Bs + byt);
      }
#pragma unroll
      for (int mi = 0; mi < 4; ++mi)
#pragma unroll
        for (int ni = 0; ni < 4; ++ni)
          acc[mi][ni] = __builtin_amdgcn_mfma_f32_16x16x32_bf16(
              af[mi], bfv[ni], acc[mi][ni], 0, 0, 0);
    }
  }

#pragma unroll
  for (int ni = 0; ni < 4; ++ni) {
    const int n = bcol * 128 + wn * 64 + ni * 16 + l15;
    const float bn = bias[n];
#pragma unroll
    for (int mi = 0; mi < 4; ++mi) {
      const int mb = brow * 128 + wm * 64 + mi * 16 + l4 * 4;
#pragma unroll
      for (int r = 0; r < 4; ++r) {
        const float v = acc[mi][ni][r] + bn;
        const int m = mb + r;
        const int b_ = m >> 11, tok = m & 2047, h_ = n >> 6, d = n & 63;
        if (seg < 2) {
          ((u16*)outp)[(((size_t)(b_ * 16 + h_) * 2048 + tok) << 6) + d] = f2bf(v * scale);
        } else {
          ((u16*)outp)[(((size_t)(b_ * 16 + h_) * 64 + d) << 11) + tok] = f2bf(v);
        }
      }
    }
  }
}

// ---------------- output projection GEMM (R9: bf16 A, f32 out, 2-barrier) ----------------
__global__ __launch_bounds__(256) void out_gemm(const u16* __restrict__ A,
                                                const u16* __restrict__ Wg,
                                                const float* __restrict__ bias,
                                                float* __restrict__ outp) {
  __shared__ __align__(16) char As[16384];
  __shared__ __align__(16) char Bs[16384];
  const int t = threadIdx.x;
  const int lane = t & 63;
  const int w = t >> 6;
  const int wm = w >> 1, wn = w & 1;
  const int l15 = lane & 15, l4 = lane >> 4;

  const int bid = blockIdx.x;
  const int swz = (bid & 7) * 64 + (bid >> 3);
  const int brow = swz >> 3;
  const int bcol = swz & 7;

  f32x4 acc[4][4] = {};

  const int srow = t >> 3;
  const int sbyte = (t & 7) * 16;

  for (int kt = 0; kt < 16; ++kt) {
    const int k0 = kt * 64;
    __syncthreads();
#pragma unroll
    for (int i = 0; i < 4; ++i) {
      const int r = i * 32 + srow;
      const int sb = sbyte ^ ((r & 7) << 4);
      GLOAD16((const char*)(A + (size_t)(brow * 128 + r) * 1024 + k0) + sb,
              As + i * 4096 + t * 16);
      GLOAD16((const char*)(Wg + (size_t)(bcol * 128 + r) * 1024 + k0) + sb,
              Bs + i * 4096 + t * 16);
    }
    __syncthreads();
#pragma unroll
    for (int kf = 0; kf < 2; ++kf) {
      short8 af[4], bfv[4];
#pragma unroll
      for (int mi = 0; mi < 4; ++mi) {
        const int r = wm * 64 + mi * 16 + l15;
        af[mi] = *(const short8*)(As + r * 128 + ((kf * 64 + l4 * 16) ^ ((r & 7) << 4)));
      }
#pragma unroll
      for (int ni = 0; ni < 4; ++ni) {
        const int r = wn * 64 + ni * 16 + l15;
        bfv[ni] = *(const short8*)(Bs + r * 128 + ((kf * 64 + l4 * 16) ^ ((r & 7) << 4)));
      }
#pragma unroll
      for (int mi = 0; mi < 4; ++mi)
#pragma unroll
        for (int ni = 0; ni < 4; ++ni)
          acc[mi][ni] = __builtin_amdgcn_mfma_f32_16x16x32_bf16(
              af[mi], bfv[ni], acc[mi][ni], 0, 0, 0);
    }
  }

#pragma unroll
  for (int ni = 0; ni < 4; ++ni) {
    const int n = bcol * 128 + wn * 64 + ni * 16 + l15;
    const float bn = bias[n];
#pragma unroll
    for (int mi = 0; mi < 4; ++mi) {
      const int mb = brow * 128 + wm * 64 + mi * 16 + l4 * 4;
#pragma unroll
      for (int r = 0; r < 4; ++r)
        outp[(size_t)(mb + r) * 1024 + n] = acc[mi][ni][r] + bn;
    }
  }
}

// ---------------- Flash attention v5 (R6/R9, 111 us) ----------------
__global__ __launch_bounds__(256, 2) void attn_fwd5(const u16* __restrict__ Q,
                                                    const u16* __restrict__ Kp,
                                                    const u16* __restrict__ Vt,
                                                    const int* __restrict__ mask,
                                                    u16* __restrict__ ctx) {
  __shared__ u16 Ks[2][64 * 64];
  __shared__ u16 Vs[2][64 * 64];

  const int t = threadIdx.x, lane = t & 63, w = t >> 6;
  const int q31 = lane & 31, hi = lane >> 5;

  const int bid = blockIdx.x;
  const int swz = (bid & 7) * 64 + (bid >> 3);
  const int bh = swz >> 3;
  const int b_ = bh >> 4, h_ = bh & 15;
  const int q0 = (swz & 7) * 256 + w * 64;
  const size_t headO = (size_t)bh * 131072;

  short8 qfA[4], qfB[4];
  {
    const u16* qrowA = Q + headO + (size_t)(q0 + q31) * 64 + hi * 8;
    const u16* qrowB = qrowA + 32 * 64;
#pragma unroll
    for (int ds = 0; ds < 4; ++ds) {
      qfA[ds] = *(const short8*)(qrowA + ds * 16);
      qfB[ds] = *(const short8*)(qrowB + ds * 16);
    }
  }

  const int srow = t >> 3;
  const int sbyte = (t & 7) * 16;

#define STAGE_KV(bufi, kb)                                                      \
  {                                                                             \
    _Pragma("unroll") for (int i = 0; i < 2; ++i) {                             \
      const int r = i * 32 + srow;                                              \
      const int sb = sbyte ^ ((r & 7) << 4);                                    \
      GLOAD16((const char*)(Kp + headO + (size_t)((kb) + r) * 64) + sb,         \
              &Ks[bufi][(i * 4096 + t * 16) >> 1]);                             \
      GLOAD16((const char*)(Vt + headO + (size_t)r * 2048 + (kb)) + sb,         \
              &Vs[bufi][(i * 4096 + t * 16) >> 1]);                             \
    }                                                                           \
  }

#define PACK(sv, pfa, pfb)                                                      \
  {                                                                             \
    const unsigned w0 = cvtpk(sv[0], sv[1]),   w1 = cvtpk(sv[2], sv[3]);        \
    const unsigned w2 = cvtpk(sv[4], sv[5]),   w3 = cvtpk(sv[6], sv[7]);        \
    const unsigned w4 = cvtpk(sv[8], sv[9]),   w5 = cvtpk(sv[10], sv[11]);      \
    const unsigned w6 = cvtpk(sv[12], sv[13]), w7 = cvtpk(sv[14], sv[15]);      \
    const unsigned x0 = (unsigned)__shfl_xor((int)(hi ? w0 : w2), 32);          \
    const unsigned x1 = (unsigned)__shfl_xor((int)(hi ? w1 : w3), 32);          \
    const unsigned y0 = (unsigned)__shfl_xor((int)(hi ? w4 : w6), 32);          \
    const unsigned y1 = (unsigned)__shfl_xor((int)(hi ? w5 : w7), 32);          \
    u32x4 fa = hi ? (u32x4){x0, x1, w2, w3} : (u32x4){w0, w1, x0, x1};          \
    u32x4 fb = hi ? (u32x4){y0, y1, w6, w7} : (u32x4){w4, w5, y0, y1};          \
    pfa = __builtin_bit_cast(short8, fa);                                       \
    pfb = __builtin_bit_cast(short8, fb);                                       \
  }

  f32x16 oA0 = {}, oA1 = {}, oB0 = {}, oB1 = {};
  float lA = 0.f, lB = 0.f;
  const int kcol = hi * 16;
  const int rswz = (q31 & 7) << 4;

  STAGE_KV(0, 0);
  int mk = mask[b_ * 2048 + lane];
  __syncthreads();

  int buf = 0;
  for (int kt = 0; kt < 32; ++kt) {
    const int kb = kt * 64;
    if (kt + 1 < 32) STAGE_KV(buf ^ 1, kb + 64);
    const int mk_next = (kt + 1 < 32) ? mask[b_ * 2048 + kb + 64 + lane] : 0;
    const u64 bits = __ballot(mk != 0);

#pragma unroll
    for (int half = 0; half < 2; ++half) {
      f32x16 sA = {}, sB = {};
      __builtin_amdgcn_s_setprio(1);
#pragma unroll
      for (int ds = 0; ds < 4; ++ds) {
        const int byt = (half * 32 + q31) * 128 + ((ds * 32 + kcol) ^ rswz);
        short8 ka = *(const short8*)&Ks[buf][byt >> 1];
        sA = __builtin_amdgcn_mfma_f32_32x32x16_bf16(ka, qfA[ds], sA, 0, 0, 0);
        sB = __builtin_amdgcn_mfma_f32_32x32x16_bf16(ka, qfB[ds], sB, 0, 0, 0);
      }
      __builtin_amdgcn_s_setprio(0);

      if (bits == ~0ull) {
#pragma unroll
        for (int r = 0; r < 16; ++r) { sA[r] = fexp2(sA[r]); sB[r] = fexp2(sB[r]); }
      } else {
#pragma unroll
        for (int r = 0; r < 16; ++r) {
          const int k0 = half * 32 + (r & 3) + 8 * (r >> 2) + 4 * hi;
          const bool on = (bits >> k0) & 1;
          sA[r] = on ? fexp2(sA[r]) : 0.f;
          sB[r] = on ? fexp2(sB[r]) : 0.f;
        }
      }

      {
        float a0 = 0.f, a1 = 0.f, b0 = 0.f, b1 = 0.f;
#pragma unroll
        for (int r = 0; r < 16; r += 2) {
          a0 += sA[r]; a1 += sA[r + 1];
          b0 += sB[r]; b1 += sB[r + 1];
        }
        lA += a0 + a1;
        lB += b0 + b1;
      }

      short8 pA0, pA1, pB0, pB1;
      PACK(sA, pA0, pA1);
      PACK(sB, pB0, pB1);

      __builtin_amdgcn_s_setprio(1);
      {
        const int rb0 = q31 * 128, rb1 = (32 + q31) * 128;
        const int c0 = (half * 64 + kcol) ^ rswz;
        const int c1 = (half * 64 + 32 + kcol) ^ rswz;
        short8 va;
        va = *(const short8*)&Vs[buf][(rb0 + c0) >> 1];
        oA0 = __builtin_amdgcn_mfma_f32_32x32x16_bf16(va, pA0, oA0, 0, 0, 0);
        oB0 = __builtin_amdgcn_mfma_f32_32x32x16_bf16(va, pB0, oB0, 0, 0, 0);
        va = *(const short8*)&Vs[buf][(rb0 + c1) >> 1];
        oA0 = __builtin_amdgcn_mfma_f32_32x32x16_bf16(va, pA1, oA0, 0, 0, 0);
        oB0 = __builtin_amdgcn_mfma_f32_32x32x16_bf16(va, pB1, oB0, 0, 0, 0);
        va = *(const short8*)&Vs[buf][(rb1 + c0) >> 1];
        oA1 = __builtin_amdgcn_mfma_f32_32x32x16_bf16(va, pA0, oA1, 0, 0, 0);
        oB1 = __builtin_amdgcn_mfma_f32_32x32x16_bf16(va, pB0, oB1, 0, 0, 0);
        va = *(const short8*)&Vs[buf][(rb1 + c1) >> 1];
        oA1 = __builtin_amdgcn_mfma_f32_32x32x16_bf16(va, pA1, oA1, 0, 0, 0);
        oB1 = __builtin_amdgcn_mfma_f32_32x32x16_bf16(va, pB1, oB1, 0, 0, 0);
      }
      __builtin_amdgcn_s_setprio(0);
    }

    mk = mk_next;
    __syncthreads();
    buf ^= 1;
  }
#undef STAGE_KV

  lA += __shfl_xor(lA, 32);
  lB += __shfl_xor(lB, 32);
  const float invA = lA > 0.f ? 1.f / lA : 0.f;
  const float invB = lB > 0.f ? 1.f / lB : 0.f;
  const int tokA = q0 + q31;
  u16* crowA = ctx + ((size_t)b_ * 2048 + tokA) * 1024 + h_ * 64 + 4 * hi;
  u16* crowB = crowA + 32 * 1024;
#pragma unroll
  for (int g = 0; g < 4; ++g) {
    unsigned u0, u1;
    u0 = cvtpk(oA0[4 * g + 0] * invA, oA0[4 * g + 1] * invA);
    u1 = cvtpk(oA0[4 * g + 2] * invA, oA0[4 * g + 3] * invA);
    *(uint2*)(crowA + 8 * g) = make_uint2(u0, u1);
    u0 = cvtpk(oA1[4 * g + 0] * invA, oA1[4 * g + 1] * invA);
    u1 = cvtpk(oA1[4 * g + 2] * invA, oA1[4 * g + 3] * invA);
    *(uint2*)(crowA + 32 + 8 * g) = make_uint2(u0, u1);
    u0 = cvtpk(oB0[4 * g + 0] * invB, oB0[4 * g + 1] * invB);
    u1 = cvtpk(oB0[4 * g + 2] * invB, oB0[4 * g + 3] * invB);
    *(uint2*)(crowB + 8 * g) = make_uint2(u0, u1);
    u0 = cvtpk(oB1[4 * g + 0] * invB, oB1[4 * g + 1] * invB);
    u1 = cvtpk(oB1[4 * g + 2] * invB, oB1[4 * g + 3] * invB);
    *(uint2*)(crowB + 32 + 8 * g) = make_uint2(u0, u1);
  }
}

// ---------------- host launcher ----------------
extern "C" void kernel_launch(void* const* d_in, const int* in_sizes, int n_in,
                              void* d_out, int out_size, void* d_ws, size_t ws_size,
                              hipStream_t stream) {
  const float* q_in = (const float*)d_in[0];
  const float* k_in = (const float*)d_in[1];
  const float* v_in = (const float*)d_in[2];
  const int*   mask = (const int*)d_in[3];
  const float* Wq = (const float*)d_in[4];
  const float* bq = (const float*)d_in[5];
  const float* Wk = (const float*)d_in[6];
  const float* bk = (const float*)d_in[7];
  const float* Wv = (const float*)d_in[8];
  const float* bv = (const float*)d_in[9];
  const float* Wo = (const float*)d_in[10];
  const float* bo = (const float*)d_in[11];
  float* out = (float*)d_out;

  char* ws = (char*)d_ws;
  u16* ctx = (u16*)(ws);                       // [B,T,F] bf16 attn output
  u16* Qp = (u16*)(ws + 50331648);             // [B,h,T,dk], pre-scaled
  u16* Kp = (u16*)(ws + 67108864);             // [B,h,T,dk]
  u16* Vtb = (u16*)(ws + 83886080);            // [B,h,dk,T]
  u16* wqb = (u16*)(ws + 100663296);           // bf16 weights, 2 MiB each
  u16* wkb = (u16*)(ws + 102760448);
  u16* wvb = (u16*)(ws + 104857600);
  u16* wob = (u16*)(ws + 106954752);

  // weights f32 -> bf16 (4 x 2^18 float4)
  CvtArgs wts;
  wts.src[0] = Wq;  wts.src[1] = Wk;  wts.src[2] = Wv;  wts.src[3] = Wo;
  wts.dst[0] = wqb; wts.dst[1] = wkb; wts.dst[2] = wvb; wts.dst[3] = wob;
  cvt_multi<<<4 * 1024, 256, 0, stream>>>(wts, 18);

  // merged Q/K/V projections (R9 per-block structure; one launch)
  QKVArgs qa;
  qa.A[0] = q_in; qa.A[1] = k_in; qa.A[2] = v_in;
  qa.W[0] = wqb;  qa.W[1] = wkb;  qa.W[2] = wvb;
  qa.bias[0] = bq; qa.bias[1] = bk; qa.bias[2] = bv;
  qa.out[0] = Qp;  qa.out[1] = Kp;  qa.out[2] = Vtb;
  qkv3_gemm<<<1536, 256, 0, stream>>>(qa);

  attn_fwd5<<<512, 256, 0, stream>>>(Qp, Kp, Vtb, mask, ctx);

  out_gemm<<<512, 256, 0, stream>>>(ctx, wob, bo, out);
}

// Round 12
// 217.605 us; speedup vs baseline: 1.1852x; 1.0363x over previous
//
#include <hip/hip_runtime.h>
#include <hip/hip_bf16.h>

// MultiHeadedAttention: B=4, T=2048, F=1024, h=16, dk=64.
// weights cvt -> 3 proj GEMMs (f32 A converted at staging into bf16 LDS;
// Q pre-scaled, V transposed) -> attn v5 -> out GEMM.

typedef unsigned short u16;
typedef unsigned long long u64;
typedef __attribute__((ext_vector_type(8))) short short8;
typedef __attribute__((ext_vector_type(4))) float f32x4;
typedef __attribute__((ext_vector_type(16))) float f32x16;
typedef __attribute__((ext_vector_type(4))) unsigned int u32x4;

#define GLOAD16(g, l) __builtin_amdgcn_global_load_lds( \
    (const __attribute__((address_space(1))) unsigned int*)(g), \
    (__attribute__((address_space(3))) unsigned int*)(l), 16, 0, 0)

__device__ __forceinline__ u16 f2bf(float x) {
  unsigned int u = __float_as_uint(x);
  return (u16)((u + 0x7fffu + ((u >> 16) & 1u)) >> 16);  // RNE, finite inputs
}

__device__ __forceinline__ float fexp2(float x) {
#if __has_builtin(__builtin_amdgcn_exp2f)
  return __builtin_amdgcn_exp2f(x);
#else
  return exp2f(x);
#endif
}

__device__ __forceinline__ unsigned cvtpk(float lo, float hi) {
  unsigned r;
  asm("v_cvt_pk_bf16_f32 %0, %1, %2" : "=v"(r) : "v"(lo), "v"(hi));
  return r;
}

// ---------------- f32 -> bf16 multi-tensor convert (weights) ----------------
struct CvtArgs {
  const float* src[4];
  u16* dst[4];
};

__global__ __launch_bounds__(256) void cvt_multi(CvtArgs a, int shift) {
  const int id = blockIdx.x * 256 + threadIdx.x;
  const int seg = id >> shift;
  const int off = id & ((1 << shift) - 1);
  float4 v = ((const float4*)a.src[seg])[off];
  ushort4 o;
  o.x = f2bf(v.x); o.y = f2bf(v.y); o.z = f2bf(v.z); o.w = f2bf(v.w);
  ((ushort4*)a.dst[seg])[off] = o;
}

// ---------------- GEMM: C[M,N] = A[M,K] * B[N,K]^T + bias ----------------
// M=8192, N=K=1024. 128x128 tile, BK=64, 256 threads (4 waves, 2x2), 2-barrier loop.
// AF32=1: A f32 in global, reg-staged coalesced + cvt_pk + swizzled ds_write (bf16 LDS).
// AF32=0: A bf16 in global, staged via global_load_lds.
// Both paths: As/Bs 16KB each (32KB total -> 5 blocks/CU), identical fragment reads.
// EPI 0: bf16 out [B,h,T,dk], scaled. EPI 1: f32 out [M,N]. EPI 2: bf16 out [B,h,dk,T].
template <int EPI, int AF32>
__global__ __launch_bounds__(256) void gemm_bt(const void* __restrict__ Ap,
                                               const u16* __restrict__ Bw,
                                               const float* __restrict__ bias,
                                               void* __restrict__ Cout,
                                               float scale) {
  __shared__ __align__(16) char As[16384];
  __shared__ __align__(16) char Bs[16384];
  const int t = threadIdx.x;
  const int lane = t & 63;
  const int w = t >> 6;
  const int wm = w >> 1, wn = w & 1;
  const int l15 = lane & 15, l4 = lane >> 4;

  const int bid = blockIdx.x;
  const int swz = (bid & 7) * 64 + (bid >> 3);
  const int brow = swz >> 3;  // 64 M-tiles
  const int bcol = swz & 7;   // 8 N-tiles

  f32x4 acc[4][4] = {};

  const int srow = t >> 3;          // 0..31  (bf16 16B-granule staging)
  const int sbyte = (t & 7) * 16;   // 0..112
  const int arj = t >> 4;           // 0..15  (f32 reg-staging: row within group)
  const int acol = t & 15;          // 16B f32 chunk (4 f32)

  for (int kt = 0; kt < 16; ++kt) {
    const int k0 = kt * 64;
    __syncthreads();
    if constexpr (AF32) {
      const float* Ag = (const float*)Ap;
      float4 areg[8];
#pragma unroll
      for (int j = 0; j < 8; ++j)
        areg[j] = *(const float4*)(Ag + (size_t)(brow * 128 + j * 16 + arj) * 1024 +
                                   k0 + acol * 4);
#pragma unroll
      for (int i = 0; i < 4; ++i) {
        const int r = i * 32 + srow;
        const int sb = sbyte ^ ((r & 7) << 4);
        GLOAD16((const char*)(Bw + (size_t)(bcol * 128 + r) * 1024 + k0) + sb,
                Bs + i * 4096 + t * 16);
      }
#pragma unroll
      for (int j = 0; j < 8; ++j) {
        const int r = j * 16 + arj;
        uint2 pk = make_uint2(cvtpk(areg[j].x, areg[j].y), cvtpk(areg[j].z, areg[j].w));
        *(uint2*)(As + r * 128 + ((acol * 8) ^ ((r & 7) << 4))) = pk;
      }
    } else {
      const u16* Ag = (const u16*)Ap;
#pragma unroll
      for (int i = 0; i < 4; ++i) {
        const int r = i * 32 + srow;
        const int sb = sbyte ^ ((r & 7) << 4);
        GLOAD16((const char*)(Ag + (size_t)(brow * 128 + r) * 1024 + k0) + sb,
                As + i * 4096 + t * 16);
        GLOAD16((const char*)(Bw + (size_t)(bcol * 128 + r) * 1024 + k0) + sb,
                Bs + i * 4096 + t * 16);
      }
    }
    __syncthreads();
#pragma unroll
    for (int kf = 0; kf < 2; ++kf) {
      short8 af[4], bfv[4];
#pragma unroll
      for (int mi = 0; mi < 4; ++mi) {
        const int r = wm * 64 + mi * 16 + l15;
        af[mi] = *(const short8*)(As + r * 128 + ((kf * 64 + l4 * 16) ^ ((r & 7) << 4)));
      }
#pragma unroll
      for (int ni = 0; ni < 4; ++ni) {
        const int r = wn * 64 + ni * 16 + l15;
        bfv[ni] = *(const short8*)(Bs + r * 128 + ((kf * 64 + l4 * 16) ^ ((r & 7) << 4)));
      }
#pragma unroll
      for (int mi = 0; mi < 4; ++mi)
#pragma unroll
        for (int ni = 0; ni < 4; ++ni)
          acc[mi][ni] = __builtin_amdgcn_mfma_f32_16x16x32_bf16(
              af[mi], bfv[ni], acc[mi][ni], 0, 0, 0);
    }
  }

#pragma unroll
  for (int ni = 0; ni < 4; ++ni) {
    const int n = bcol * 128 + wn * 64 + ni * 16 + l15;
    const float bn = bias[n];
#pragma unroll
    for (int mi = 0; mi < 4; ++mi) {
      const int mb = brow * 128 + wm * 64 + mi * 16 + l4 * 4;
#pragma unroll
      for (int r = 0; r < 4; ++r) {
        const float v = acc[mi][ni][r] + bn;
        const int m = mb + r;
        const int b_ = m >> 11, tok = m & 2047, h_ = n >> 6, d = n & 63;
        if (EPI == 0) {
          ((u16*)Cout)[(((size_t)(b_ * 16 + h_) * 2048 + tok) << 6) + d] = f2bf(v * scale);
        } else if (EPI == 2) {
          ((u16*)Cout)[(((size_t)(b_ * 16 + h_) * 64 + d) << 11) + tok] = f2bf(v);
        } else {
          ((float*)Cout)[(size_t)m * 1024 + n] = v;
        }
      }
    }
  }
}

// ---------------- Flash attention v5 (R6/R9, 111 us) ----------------
__global__ __launch_bounds__(256, 2) void attn_fwd5(const u16* __restrict__ Q,
                                                    const u16* __restrict__ Kp,
                                                    const u16* __restrict__ Vt,
                                                    const int* __restrict__ mask,
                                                    u16* __restrict__ ctx) {
  __shared__ u16 Ks[2][64 * 64];
  __shared__ u16 Vs[2][64 * 64];

  const int t = threadIdx.x, lane = t & 63, w = t >> 6;
  const int q31 = lane & 31, hi = lane >> 5;

  const int bid = blockIdx.x;
  const int swz = (bid & 7) * 64 + (bid >> 3);
  const int bh = swz >> 3;
  const int b_ = bh >> 4, h_ = bh & 15;
  const int q0 = (swz & 7) * 256 + w * 64;
  const size_t headO = (size_t)bh * 131072;

  short8 qfA[4], qfB[4];
  {
    const u16* qrowA = Q + headO + (size_t)(q0 + q31) * 64 + hi * 8;
    const u16* qrowB = qrowA + 32 * 64;
#pragma unroll
    for (int ds = 0; ds < 4; ++ds) {
      qfA[ds] = *(const short8*)(qrowA + ds * 16);
      qfB[ds] = *(const short8*)(qrowB + ds * 16);
    }
  }

  const int srow = t >> 3;
  const int sbyte = (t & 7) * 16;

#define STAGE_KV(bufi, kb)                                                      \
  {                                                                             \
    _Pragma("unroll") for (int i = 0; i < 2; ++i) {                             \
      const int r = i * 32 + srow;                                              \
      const int sb = sbyte ^ ((r & 7) << 4);                                    \
      GLOAD16((const char*)(Kp + headO + (size_t)((kb) + r) * 64) + sb,         \
              &Ks[bufi][(i * 4096 + t * 16) >> 1]);                             \
      GLOAD16((const char*)(Vt + headO + (size_t)r * 2048 + (kb)) + sb,         \
              &Vs[bufi][(i * 4096 + t * 16) >> 1]);                             \
    }                                                                           \
  }

#define PACK(sv, pfa, pfb)                                                      \
  {                                                                             \
    const unsigned w0 = cvtpk(sv[0], sv[1]),   w1 = cvtpk(sv[2], sv[3]);        \
    const unsigned w2 = cvtpk(sv[4], sv[5]),   w3 = cvtpk(sv[6], sv[7]);        \
    const unsigned w4 = cvtpk(sv[8], sv[9]),   w5 = cvtpk(sv[10], sv[11]);      \
    const unsigned w6 = cvtpk(sv[12], sv[13]), w7 = cvtpk(sv[14], sv[15]);      \
    const unsigned x0 = (unsigned)__shfl_xor((int)(hi ? w0 : w2), 32);          \
    const unsigned x1 = (unsigned)__shfl_xor((int)(hi ? w1 : w3), 32);          \
    const unsigned y0 = (unsigned)__shfl_xor((int)(hi ? w4 : w6), 32);          \
    const unsigned y1 = (unsigned)__shfl_xor((int)(hi ? w5 : w7), 32);          \
    u32x4 fa = hi ? (u32x4){x0, x1, w2, w3} : (u32x4){w0, w1, x0, x1};          \
    u32x4 fb = hi ? (u32x4){y0, y1, w6, w7} : (u32x4){w4, w5, y0, y1};          \
    pfa = __builtin_bit_cast(short8, fa);                                       \
    pfb = __builtin_bit_cast(short8, fb);                                       \
  }

  f32x16 oA0 = {}, oA1 = {}, oB0 = {}, oB1 = {};
  float lA = 0.f, lB = 0.f;
  const int kcol = hi * 16;
  const int rswz = (q31 & 7) << 4;

  STAGE_KV(0, 0);
  int mk = mask[b_ * 2048 + lane];
  __syncthreads();

  int buf = 0;
  for (int kt = 0; kt < 32; ++kt) {
    const int kb = kt * 64;
    if (kt + 1 < 32) STAGE_KV(buf ^ 1, kb + 64);
    const int mk_next = (kt + 1 < 32) ? mask[b_ * 2048 + kb + 64 + lane] : 0;
    const u64 bits = __ballot(mk != 0);

#pragma unroll
    for (int half = 0; half < 2; ++half) {
      f32x16 sA = {}, sB = {};
      __builtin_amdgcn_s_setprio(1);
#pragma unroll
      for (int ds = 0; ds < 4; ++ds) {
        const int byt = (half * 32 + q31) * 128 + ((ds * 32 + kcol) ^ rswz);
        short8 ka = *(const short8*)&Ks[buf][byt >> 1];
        sA = __builtin_amdgcn_mfma_f32_32x32x16_bf16(ka, qfA[ds], sA, 0, 0, 0);
        sB = __builtin_amdgcn_mfma_f32_32x32x16_bf16(ka, qfB[ds], sB, 0, 0, 0);
      }
      __builtin_amdgcn_s_setprio(0);

      if (bits == ~0ull) {
#pragma unroll
        for (int r = 0; r < 16; ++r) { sA[r] = fexp2(sA[r]); sB[r] = fexp2(sB[r]); }
      } else {
#pragma unroll
        for (int r = 0; r < 16; ++r) {
          const int k0 = half * 32 + (r & 3) + 8 * (r >> 2) + 4 * hi;
          const bool on = (bits >> k0) & 1;
          sA[r] = on ? fexp2(sA[r]) : 0.f;
          sB[r] = on ? fexp2(sB[r]) : 0.f;
        }
      }

      {
        float a0 = 0.f, a1 = 0.f, b0 = 0.f, b1 = 0.f;
#pragma unroll
        for (int r = 0; r < 16; r += 2) {
          a0 += sA[r]; a1 += sA[r + 1];
          b0 += sB[r]; b1 += sB[r + 1];
        }
        lA += a0 + a1;
        lB += b0 + b1;
      }

      short8 pA0, pA1, pB0, pB1;
      PACK(sA, pA0, pA1);
      PACK(sB, pB0, pB1);

      __builtin_amdgcn_s_setprio(1);
      {
        const int rb0 = q31 * 128, rb1 = (32 + q31) * 128;
        const int c0 = (half * 64 + kcol) ^ rswz;
        const int c1 = (half * 64 + 32 + kcol) ^ rswz;
        short8 va;
        va = *(const short8*)&Vs[buf][(rb0 + c0) >> 1];
        oA0 = __builtin_amdgcn_mfma_f32_32x32x16_bf16(va, pA0, oA0, 0, 0, 0);
        oB0 = __builtin_amdgcn_mfma_f32_32x32x16_bf16(va, pB0, oB0, 0, 0, 0);
        va = *(const short8*)&Vs[buf][(rb0 + c1) >> 1];
        oA0 = __builtin_amdgcn_mfma_f32_32x32x16_bf16(va, pA1, oA0, 0, 0, 0);
        oB0 = __builtin_amdgcn_mfma_f32_32x32x16_bf16(va, pB1, oB0, 0, 0, 0);
        va = *(const short8*)&Vs[buf][(rb1 + c0) >> 1];
        oA1 = __builtin_amdgcn_mfma_f32_32x32x16_bf16(va, pA0, oA1, 0, 0, 0);
        oB1 = __builtin_amdgcn_mfma_f32_32x32x16_bf16(va, pB0, oB1, 0, 0, 0);
        va = *(const short8*)&Vs[buf][(rb1 + c1) >> 1];
        oA1 = __builtin_amdgcn_mfma_f32_32x32x16_bf16(va, pA1, oA1, 0, 0, 0);
        oB1 = __builtin_amdgcn_mfma_f32_32x32x16_bf16(va, pB1, oB1, 0, 0, 0);
      }
      __builtin_amdgcn_s_setprio(0);
    }

    mk = mk_next;
    __syncthreads();
    buf ^= 1;
  }
#undef STAGE_KV

  lA += __shfl_xor(lA, 32);
  lB += __shfl_xor(lB, 32);
  const float invA = lA > 0.f ? 1.f / lA : 0.f;
  const float invB = lB > 0.f ? 1.f / lB : 0.f;
  const int tokA = q0 + q31;
  u16* crowA = ctx + ((size_t)b_ * 2048 + tokA) * 1024 + h_ * 64 + 4 * hi;
  u16* crowB = crowA + 32 * 1024;
#pragma unroll
  for (int g = 0; g < 4; ++g) {
    unsigned u0, u1;
    u0 = cvtpk(oA0[4 * g + 0] * invA, oA0[4 * g + 1] * invA);
    u1 = cvtpk(oA0[4 * g + 2] * invA, oA0[4 * g + 3] * invA);
    *(uint2*)(crowA + 8 * g) = make_uint2(u0, u1);
    u0 = cvtpk(oA1[4 * g + 0] * invA, oA1[4 * g + 1] * invA);
    u1 = cvtpk(oA1[4 * g + 2] * invA, oA1[4 * g + 3] * invA);
    *(uint2*)(crowA + 32 + 8 * g) = make_uint2(u0, u1);
    u0 = cvtpk(oB0[4 * g + 0] * invB, oB0[4 * g + 1] * invB);
    u1 = cvtpk(oB0[4 * g + 2] * invB, oB0[4 * g + 3] * invB);
    *(uint2*)(crowB + 8 * g) = make_uint2(u0, u1);
    u0 = cvtpk(oB1[4 * g + 0] * invB, oB1[4 * g + 1] * invB);
    u1 = cvtpk(oB1[4 * g + 2] * invB, oB1[4 * g + 3] * invB);
    *(uint2*)(crowB + 32 + 8 * g) = make_uint2(u0, u1);
  }
}

// ---------------- host launcher ----------------
extern "C" void kernel_launch(void* const* d_in, const int* in_sizes, int n_in,
                              void* d_out, int out_size, void* d_ws, size_t ws_size,
                              hipStream_t stream) {
  const float* q_in = (const float*)d_in[0];
  const float* k_in = (const float*)d_in[1];
  const float* v_in = (const float*)d_in[2];
  const int*   mask = (const int*)d_in[3];
  const float* Wq = (const float*)d_in[4];
  const float* bq = (const float*)d_in[5];
  const float* Wk = (const float*)d_in[6];
  const float* bk = (const float*)d_in[7];
  const float* Wv = (const float*)d_in[8];
  const float* bv = (const float*)d_in[9];
  const float* Wo = (const float*)d_in[10];
  const float* bo = (const float*)d_in[11];
  float* out = (float*)d_out;

  char* ws = (char*)d_ws;
  u16* ctx = (u16*)(ws);                       // [B,T,F] bf16 attn output
  u16* Qp = (u16*)(ws + 50331648);             // [B,h,T,dk], pre-scaled
  u16* Kp = (u16*)(ws + 67108864);             // [B,h,T,dk]
  u16* Vtb = (u16*)(ws + 83886080);            // [B,h,dk,T]
  u16* wqb = (u16*)(ws + 100663296);           // bf16 weights, 2 MiB each
  u16* wkb = (u16*)(ws + 102760448);
  u16* wvb = (u16*)(ws + 104857600);
  u16* wob = (u16*)(ws + 106954752);

  // weights f32 -> bf16 (4 x 2^18 float4)
  CvtArgs wts;
  wts.src[0] = Wq;  wts.src[1] = Wk;  wts.src[2] = Wv;  wts.src[3] = Wo;
  wts.dst[0] = wqb; wts.dst[1] = wkb; wts.dst[2] = wvb; wts.dst[3] = wob;
  cvt_multi<<<4 * 1024, 256, 0, stream>>>(wts, 18);

  const float C_SCALE = 0.18033688011112042f;  // (1/sqrt(64)) * log2(e)
  // projections: separate launches (per-XCD L2 working set stays fit)
  gemm_bt<0, 1><<<512, 256, 0, stream>>>(q_in, wqb, bq, Qp, C_SCALE);
  gemm_bt<0, 1><<<512, 256, 0, stream>>>(k_in, wkb, bk, Kp, 1.0f);
  gemm_bt<2, 1><<<512, 256, 0, stream>>>(v_in, wvb, bv, Vtb, 1.0f);

  attn_fwd5<<<512, 256, 0, stream>>>(Qp, Kp, Vtb, mask, ctx);

  gemm_bt<1, 0><<<512, 256, 0, stream>>>(ctx, wob, bo, out, 1.0f);
}